// Round 1
// baseline (742.654 us; speedup 1.0000x reference)
//
#include <hip/hip_runtime.h>
#include <math.h>

// Problem constants (B,T,H,K,V,BT) = (2,8192,16,32,64,64)
#define Bb 2
#define Tt 8192
#define Hh 16
#define NT 128          // T/BT
#define NCH 4096        // NT * B * H  (chunk-heads)
// Workspace layout (floats), per chunk-head slot:
//   wsW  [NCH][64*32]  w
//   wsU  [NCH][64*64]  u
//   wsKd [NCH][64*32]  k_dec
//   wsEgl[NCH][32]     exp(g_last)
//   wsS  [NCH][32*64]  state S entering each chunk
// total = 4096*10272*4 B = 168,296,448 B (~169 MB) — must fit in d_ws.

__device__ __forceinline__ float softplusf(float x) {
  return fmaxf(x, 0.f) + log1pf(__expf(-fabsf(x)));
}

// ---------------- Phase 1: per-chunk intra quantities ----------------
__global__ __launch_bounds__(256) void kda_phase1(
    const float* __restrict__ kin, const float* __restrict__ vin,
    const float* __restrict__ graw, const float* __restrict__ beta,
    const float* __restrict__ A_log, const float* __restrict__ dt_bias,
    float* __restrict__ ws)
{
  __shared__ float sG[64*33];   // gcum (stride 33)
  __shared__ float sK[64*33];   // kn   (stride 33)
  __shared__ float sL[64*64];   // L column-major; later k_egb (s33) then vb (s64)
  __shared__ float sT[64*65];   // P(s33)+Q scratch; later Tm (stride 65)
  __shared__ float sC[16*17];   // off-diag temp

  const int tid = threadIdx.x;
  const int ch = blockIdx.x;
  const int c = ch >> 5, bh = ch & 31;
  const int b = bh >> 4, h = bh & 15;
  const int t0 = c*64;
  const int iq = tid >> 2, kq = (tid & 3)*8;   // row / k-offset mapping (4 thr per row)

  float* wsW  = ws;
  float* wsU  = ws + (size_t)NCH*2048;
  float* wsKd = ws + (size_t)NCH*(2048+4096);
  float* wsEgl= ws + (size_t)NCH*(2048+4096+2048);

  const float negA = -__expf(A_log[h]);

  { // gate g into sG
    const float* gr = graw + (((size_t)b*Tt + t0 + iq)*Hh + h)*32 + kq;
    const float* db = dt_bias + h*32 + kq;
    #pragma unroll
    for (int r = 0; r < 8; ++r)
      sG[iq*33 + kq + r] = negA * softplusf(gr[r] + db[r]);
  }
  __syncthreads();
  if (tid < 32) { // cumsum over time per k
    float acc = 0.f;
    for (int i = 0; i < 64; ++i) { acc += sG[i*33 + tid]; sG[i*33 + tid] = acc; }
  }
  { // k row-l2-normalize into sK
    const float* kp = kin + (((size_t)b*Tt + t0 + iq)*Hh + h)*32 + kq;
    float kr[8]; float ss = 0.f;
    #pragma unroll
    for (int r = 0; r < 8; ++r) { kr[r] = kp[r]; ss += kr[r]*kr[r]; }
    ss += __shfl_xor(ss, 1); ss += __shfl_xor(ss, 2);
    const float sc = 1.f / fmaxf(sqrtf(ss), 1e-6f);
    #pragma unroll
    for (int r = 0; r < 8; ++r) sK[iq*33 + kq + r] = kr[r]*sc;
  }
  __syncthreads();

  // ---- Akk in 8-column tiles: decay factorized about r = gcum[j0] ----
  const float b_cm = beta[((size_t)b*Tt + t0 + (tid & 63))*Hh + h];
  float* P = sT;            // 64x32 stride 33
  float* Q = sT + 2112;     // 8x32 stride 33
  for (int jt = 0; jt < 8; ++jt) {
    const int j0 = jt*8;
    #pragma unroll
    for (int r = 0; r < 8; ++r) {
      const int idx = iq*33 + kq + r;
      P[idx] = sK[idx] * __expf(fminf(sG[idx] - sG[j0*33 + kq + r], 0.f));
    }
    {
      const int jj = tid >> 5, kk = tid & 31;
      Q[jj*33 + kk] = sK[(j0+jj)*33 + kk] * __expf(sG[j0*33 + kk] - sG[(j0+jj)*33 + kk]);
    }
    __syncthreads();
    {
      const int i = tid & 63, jj2 = (tid >> 6)*2;
      float a0 = 0.f, a1 = 0.f;
      for (int kk = 0; kk < 32; ++kk) {
        const float p = P[i*33 + kk];
        a0 += p * Q[(jj2  )*33 + kk];
        a1 += p * Q[(jj2+1)*33 + kk];
      }
      const int j_0 = j0 + jj2;
      // L = tril_strict(Akk * beta_row), stored column-major
      sL[(j_0  )*64 + i] = (i > j_0  ) ? a0*b_cm : 0.f;
      sL[(j_0+1)*64 + i] = (i > j_0+1) ? a1*b_cm : 0.f;
    }
    __syncthreads();
  }

  // ---- Tm = (I + L)^-1, blocked 16x16 forward substitution ----
  for (int e = tid; e < 4096; e += 256) {
    const int row = e >> 6, col = e & 63;
    sT[row*65 + col] = (row == col) ? 1.f : 0.f;
  }
  __syncthreads();
  { // diagonal blocks (4 in parallel, 64 lanes)
    const int p = tid >> 4, col = tid & 15;
    for (int i = 1; i < 16; ++i) {
      if (tid < 64) {
        const int gi = p*16 + i, gc = p*16 + col;
        float acc = 0.f;
        for (int j = 0; j < i; ++j)
          acc -= sL[(p*16+j)*64 + gi] * sT[(p*16+j)*65 + gc];
        sT[gi*65 + gc] = acc + ((i == col) ? 1.f : 0.f);
      }
      __syncthreads();
    }
  }
  { // off-diagonal blocks: T_pq = -T_pp * (sum_m L_pm T_mq)
    const int ri = tid >> 4, col = tid & 15;
    for (int d = 1; d <= 3; ++d)
      for (int p = d; p < 4; ++p) {
        const int q = p - d;
        float acc = 0.f;
        for (int m = q; m < p; ++m) {
          #pragma unroll
          for (int j = 0; j < 16; ++j)
            acc += sL[(m*16+j)*64 + (p*16+ri)] * sT[(m*16+j)*65 + (q*16+col)];
        }
        sC[ri*17 + col] = acc;
        __syncthreads();
        float acc2 = 0.f;
        #pragma unroll
        for (int j = 0; j < 16; ++j)
          acc2 += sT[(p*16+ri)*65 + (p*16+j)] * sC[j*17 + col];
        sT[(p*16+ri)*65 + (q*16+col)] = -acc2;
        __syncthreads();
      }
  }

  { // k_egb = beta_j * kn * exp(gcum) (into sL, stride 33); k_dec, eg_last -> global
    const float b_row = beta[((size_t)b*Tt + t0 + iq)*Hh + h];
    #pragma unroll
    for (int r = 0; r < 8; ++r) {
      const int idx = iq*33 + kq + r;
      const float g = sG[idx], kn = sK[idx];
      sL[idx] = b_row * kn * __expf(g);
      wsKd[(size_t)ch*2048 + tid*8 + r] = kn * __expf(sG[63*33 + kq + r] - g);
    }
    if (tid < 32) wsEgl[(size_t)ch*32 + tid] = __expf(sG[63*33 + tid]);
  }
  __syncthreads();

  { // w = Tm @ k_egb  (beta folded into k_egb; Tm unit-lower explicit)
    float acc[8] = {0,0,0,0,0,0,0,0};
    for (int j = 0; j <= iq; ++j) {
      const float t = sT[iq*65 + j];
      #pragma unroll
      for (int r = 0; r < 8; ++r) acc[r] += t * sL[j*33 + kq + r];
    }
    #pragma unroll
    for (int r = 0; r < 8; ++r) wsW[(size_t)ch*2048 + tid*8 + r] = acc[r];
  }
  __syncthreads();

  { // vb = beta_j * v into sL (stride 64)
    #pragma unroll
    for (int r = 0; r < 4; ++r) {
      const int f = tid + 256*r;
      const int j = f >> 4, qd = f & 15;
      const float bj = beta[((size_t)b*Tt + t0 + j)*Hh + h];
      float4 v4 = *(const float4*)(vin + (((size_t)b*Tt + t0 + j)*Hh + h)*64 + qd*4);
      v4.x *= bj; v4.y *= bj; v4.z *= bj; v4.w *= bj;
      *(float4*)(sL + j*64 + qd*4) = v4;
    }
  }
  __syncthreads();

  { // u = Tm @ vb
    const int vs = (tid & 3)*16;
    float acc[16];
    #pragma unroll
    for (int r = 0; r < 16; ++r) acc[r] = 0.f;
    for (int j = 0; j <= iq; ++j) {
      const float t = sT[iq*65 + j];
      #pragma unroll
      for (int r = 0; r < 16; ++r) acc[r] += t * sL[j*64 + vs + r];
    }
    #pragma unroll
    for (int r = 0; r < 16; ++r) wsU[(size_t)ch*4096 + tid*16 + r] = acc[r];
  }
}

// ---------------- Phase 2: sequential state scan ----------------
// 256 blocks = 32 (b,h) x 8 v-tiles of 8 columns (V-columns evolve independently).
__global__ __launch_bounds__(256) void kda_phase2(float* __restrict__ ws)
{
  __shared__ float sW[64*33];
  __shared__ float sKd[64*33];
  __shared__ float sS[256];     // S tile 32x8
  __shared__ float sV[512];     // v_new tile 64x8
  __shared__ float sEgl[32];

  const int tid = threadIdx.x;
  const int bh = blockIdx.x >> 3, vt = blockIdx.x & 7;
  const int v0 = vt*8;

  const float* wsW  = ws;
  const float* wsU  = ws + (size_t)NCH*2048;
  const float* wsKd = ws + (size_t)NCH*(2048+4096);
  const float* wsEgl= ws + (size_t)NCH*(2048+4096+2048);
  float*       wsS  = ws + (size_t)NCH*(2048+4096+2048) + (size_t)NCH*32;

  const int iq = tid >> 2, kq = (tid & 3)*8;
  const int j2 = (tid & 3)*2;
  const int ku = tid >> 3, ju = tid & 7;

  sS[tid] = 0.f;   // S0 = 0 (ws is poisoned; init here)
  __syncthreads();

  for (int c = 0; c < 128; ++c) {
    const int ch = c*32 + bh;
    // stage w, k_dec, egl; u slice to regs; store entering-S
    float4 a0 = *(const float4*)(wsW  + (size_t)ch*2048 + tid*8);
    float4 a1 = *(const float4*)(wsW  + (size_t)ch*2048 + tid*8 + 4);
    float4 d0 = *(const float4*)(wsKd + (size_t)ch*2048 + tid*8);
    float4 d1 = *(const float4*)(wsKd + (size_t)ch*2048 + tid*8 + 4);
    sW[iq*33+kq+0]=a0.x; sW[iq*33+kq+1]=a0.y; sW[iq*33+kq+2]=a0.z; sW[iq*33+kq+3]=a0.w;
    sW[iq*33+kq+4]=a1.x; sW[iq*33+kq+5]=a1.y; sW[iq*33+kq+6]=a1.z; sW[iq*33+kq+7]=a1.w;
    sKd[iq*33+kq+0]=d0.x; sKd[iq*33+kq+1]=d0.y; sKd[iq*33+kq+2]=d0.z; sKd[iq*33+kq+3]=d0.w;
    sKd[iq*33+kq+4]=d1.x; sKd[iq*33+kq+5]=d1.y; sKd[iq*33+kq+6]=d1.z; sKd[iq*33+kq+7]=d1.w;
    if (tid < 32) sEgl[tid] = wsEgl[(size_t)ch*32 + tid];
    const float u0 = wsU[(size_t)ch*4096 + iq*64 + v0 + j2];
    const float u1 = wsU[(size_t)ch*4096 + iq*64 + v0 + j2 + 1];
    wsS[(size_t)ch*2048 + ku*64 + v0 + ju] = sS[tid];
    __syncthreads();

    // v_new = u - w @ S   (64x8)
    float acc0 = u0, acc1 = u1;
    for (int kk = 0; kk < 32; ++kk) {
      const float w = sW[iq*33 + kk];
      acc0 -= w * sS[kk*8 + j2];
      acc1 -= w * sS[kk*8 + j2 + 1];
    }
    sV[iq*8 + j2] = acc0; sV[iq*8 + j2 + 1] = acc1;
    __syncthreads();

    // S = egl * S + k_dec^T @ v_new   (32x8)
    float s = sEgl[ku] * sS[tid];
    for (int t = 0; t < 64; ++t)
      s += sKd[t*33 + ku] * sV[t*8 + ju];
    sS[tid] = s;
    __syncthreads();
  }
}

// ---------------- Phase 3: Aqk + output ----------------
__global__ __launch_bounds__(256) void kda_phase3(
    const float* __restrict__ qin, const float* __restrict__ kin,
    const float* __restrict__ graw,
    const float* __restrict__ A_log, const float* __restrict__ dt_bias,
    const float* __restrict__ ws, float* __restrict__ out)
{
  __shared__ float sG[64*33];   // gcum -> S (stride 64)
  __shared__ float sQ[64*33];   // qn -> qg
  __shared__ float sK2[64*33];  // kn -> w
  __shared__ float sA[64*65];   // Aqk
  __shared__ float sV[64*64];   // P/Q scratch -> v_new

  const int tid = threadIdx.x;
  const int ch = blockIdx.x;
  const int c = ch >> 5, bh = ch & 31;
  const int b = bh >> 4, h = bh & 15;
  const int t0 = c*64;
  const int iq = tid >> 2, kq = (tid & 3)*8;

  const float* wsW = ws;
  const float* wsU = ws + (size_t)NCH*2048;
  const float* wsS = ws + (size_t)NCH*(2048+4096+2048) + (size_t)NCH*32;

  const float negA = -__expf(A_log[h]);
  {
    const float* gr = graw + (((size_t)b*Tt + t0 + iq)*Hh + h)*32 + kq;
    const float* db = dt_bias + h*32 + kq;
    #pragma unroll
    for (int r = 0; r < 8; ++r)
      sG[iq*33 + kq + r] = negA * softplusf(gr[r] + db[r]);
  }
  __syncthreads();
  if (tid < 32) {
    float acc = 0.f;
    for (int i = 0; i < 64; ++i) { acc += sG[i*33 + tid]; sG[i*33 + tid] = acc; }
  }
  { // q (l2norm * K^-1/2) and k (l2norm)
    const float* qp = qin + (((size_t)b*Tt + t0 + iq)*Hh + h)*32 + kq;
    float qr[8]; float ssq = 0.f;
    #pragma unroll
    for (int r = 0; r < 8; ++r) { qr[r] = qp[r]; ssq += qr[r]*qr[r]; }
    ssq += __shfl_xor(ssq, 1); ssq += __shfl_xor(ssq, 2);
    const float scq = 0.17677669529663687f / fmaxf(sqrtf(ssq), 1e-6f);
    #pragma unroll
    for (int r = 0; r < 8; ++r) sQ[iq*33 + kq + r] = qr[r]*scq;

    const float* kp = kin + (((size_t)b*Tt + t0 + iq)*Hh + h)*32 + kq;
    float kr[8]; float ssk = 0.f;
    #pragma unroll
    for (int r = 0; r < 8; ++r) { kr[r] = kp[r]; ssk += kr[r]*kr[r]; }
    ssk += __shfl_xor(ssk, 1); ssk += __shfl_xor(ssk, 2);
    const float sck = 1.f / fmaxf(sqrtf(ssk), 1e-6f);
    #pragma unroll
    for (int r = 0; r < 8; ++r) sK2[iq*33 + kq + r] = kr[r]*sck;
  }
  __syncthreads();

  float* P  = sV;
  float* Qb = sV + 2112;
  for (int jt = 0; jt < 8; ++jt) {
    const int j0 = jt*8;
    #pragma unroll
    for (int r = 0; r < 8; ++r) {
      const int idx = iq*33 + kq + r;
      P[idx] = sQ[idx] * __expf(fminf(sG[idx] - sG[j0*33 + kq + r], 0.f));
    }
    {
      const int jj = tid >> 5, kk = tid & 31;
      Qb[jj*33 + kk] = sK2[(j0+jj)*33 + kk] * __expf(sG[j0*33 + kk] - sG[(j0+jj)*33 + kk]);
    }
    __syncthreads();
    {
      const int i = tid & 63, jj2 = (tid >> 6)*2;
      float a0 = 0.f, a1 = 0.f;
      for (int kk = 0; kk < 32; ++kk) {
        const float p = P[i*33 + kk];
        a0 += p * Qb[(jj2  )*33 + kk];
        a1 += p * Qb[(jj2+1)*33 + kk];
      }
      sA[i*65 + j0+jj2  ] = (i >= j0+jj2  ) ? a0 : 0.f;   // incl. diagonal
      sA[i*65 + j0+jj2+1] = (i >= j0+jj2+1) ? a1 : 0.f;
    }
    __syncthreads();
  }
  { // qg = qn * exp(gcum), in place
    #pragma unroll
    for (int r = 0; r < 8; ++r) {
      const int idx = iq*33 + kq + r;
      sQ[idx] *= __expf(sG[idx]);
    }
  }
  __syncthreads();
  { // load S into sG (stride 64) and w into sK2 (stride 33)
    #pragma unroll
    for (int r = 0; r < 2; ++r) {
      const int f = tid + 256*r;
      *(float4*)(sG + f*4) = *(const float4*)(wsS + (size_t)ch*2048 + f*4);
    }
    float4 w0 = *(const float4*)(wsW + (size_t)ch*2048 + tid*8);
    float4 w1 = *(const float4*)(wsW + (size_t)ch*2048 + tid*8 + 4);
    sK2[iq*33+kq+0]=w0.x; sK2[iq*33+kq+1]=w0.y; sK2[iq*33+kq+2]=w0.z; sK2[iq*33+kq+3]=w0.w;
    sK2[iq*33+kq+4]=w1.x; sK2[iq*33+kq+5]=w1.y; sK2[iq*33+kq+6]=w1.z; sK2[iq*33+kq+7]=w1.w;
  }
  __syncthreads();
  { // v_new = u - w @ S  into sV (stride 64)
    const int vs = (tid & 3)*16;
    float acc[16];
    #pragma unroll
    for (int rr = 0; rr < 4; ++rr) {
      float4 u4 = *(const float4*)(wsU + (size_t)ch*4096 + tid*16 + rr*4);
      acc[rr*4+0]=u4.x; acc[rr*4+1]=u4.y; acc[rr*4+2]=u4.z; acc[rr*4+3]=u4.w;
    }
    for (int kk = 0; kk < 32; ++kk) {
      const float w = sK2[iq*33 + kk];
      #pragma unroll
      for (int r = 0; r < 16; ++r) acc[r] -= w * sG[kk*64 + vs + r];
    }
    #pragma unroll
    for (int rr = 0; rr < 4; ++rr) {
      float4 o4; o4.x=acc[rr*4]; o4.y=acc[rr*4+1]; o4.z=acc[rr*4+2]; o4.w=acc[rr*4+3];
      *(float4*)(sV + iq*64 + vs + rr*4) = o4;
    }
  }
  __syncthreads();
  { // o = qg @ S + Aqk @ v_new
    const int vs = (tid & 3)*16;
    float acc[16];
    #pragma unroll
    for (int r = 0; r < 16; ++r) acc[r] = 0.f;
    for (int kk = 0; kk < 32; ++kk) {
      const float qv = sQ[iq*33 + kk];
      #pragma unroll
      for (int r = 0; r < 16; ++r) acc[r] += qv * sG[kk*64 + vs + r];
    }
    for (int j = 0; j <= iq; ++j) {
      const float av = sA[iq*65 + j];
      #pragma unroll
      for (int r = 0; r < 16; ++r) acc[r] += av * sV[j*64 + vs + r];
    }
    float* op = out + (((size_t)b*Tt + t0 + iq)*Hh + h)*64 + vs;
    #pragma unroll
    for (int rr = 0; rr < 4; ++rr) {
      float4 o4; o4.x=acc[rr*4]; o4.y=acc[rr*4+1]; o4.z=acc[rr*4+2]; o4.w=acc[rr*4+3];
      *(float4*)(op + rr*4) = o4;
    }
  }
}

extern "C" void kernel_launch(void* const* d_in, const int* in_sizes, int n_in,
                              void* d_out, int out_size, void* d_ws, size_t ws_size,
                              hipStream_t stream) {
  const float* q    = (const float*)d_in[0];
  const float* k    = (const float*)d_in[1];
  const float* v    = (const float*)d_in[2];
  const float* graw = (const float*)d_in[3];
  const float* beta = (const float*)d_in[4];
  const float* A_log= (const float*)d_in[5];
  const float* dtb  = (const float*)d_in[6];
  float* out = (float*)d_out;
  float* ws  = (float*)d_ws;
  // requires ws_size >= 4096*10272*4 = 168,296,448 bytes

  kda_phase1<<<NCH, 256, 0, stream>>>(k, v, graw, beta, A_log, dtb, ws);
  kda_phase2<<<256, 256, 0, stream>>>(ws);
  kda_phase3<<<NCH, 256, 0, stream>>>(q, k, graw, A_log, dtb, ws, out);
}

// Round 2
// 615.639 us; speedup vs baseline: 1.2063x; 1.2063x over previous
//
#include <hip/hip_runtime.h>
#include <math.h>

// Problem constants (B,T,H,K,V,BT) = (2,8192,16,32,64,64)
#define Tt 8192
#define Hh 16
#define NCH 4096        // NT * B * H  (chunk-heads), ch = c*32 + (b*16+h)
// Workspace layout (floats):
//   wsW  [NCH][2048]  w            -> overwritten by entering-S (32x64) in scanC
//   wsU  [NCH][4096]  u            -> overwritten by v_new (64x64) in scanC
//   wsM  [NCH][1024]  M = diag(egl) - Kd^T W
//   wsC  [NCH][2048]  C = Kd^T U
//   wsMs [256][1024]  per-segment composed M
//   wsCs [256][2048]  per-segment composed C
//   wsSs [256][2048]  entering S per segment
// total = (4096*9216 + 256*5120)*4 B = 156.3 MB

#define OFF_U   ((size_t)NCH*2048)
#define OFF_M   ((size_t)NCH*6144)
#define OFF_C   ((size_t)NCH*7168)
#define OFF_MS  ((size_t)NCH*9216)
#define OFF_CS  (OFF_MS + (size_t)256*1024)
#define OFF_SS  (OFF_CS + (size_t)256*2048)

__device__ __forceinline__ float softplusf(float x) {
  return fmaxf(x, 0.f) + log1pf(__expf(-fabsf(x)));
}

// ---------------- Phase 1: per-chunk intra quantities + (M,C) ----------------
__global__ __launch_bounds__(256) void kda_phase1(
    const float* __restrict__ kin, const float* __restrict__ vin,
    const float* __restrict__ graw, const float* __restrict__ beta,
    const float* __restrict__ A_log, const float* __restrict__ dt_bias,
    float* __restrict__ ws)
{
  __shared__ float sG[64*33];   // gcum -> W (stride 33)
  __shared__ float sK[64*33];   // kn -> kd (stride 33)
  __shared__ float sL[64*64];   // L col-major -> k_egb(s33) -> vb(s64) -> u(s64)
  __shared__ float sT[64*65];   // P/Q scratch -> Tm (stride 65)
  __shared__ float sC[16*17];
  __shared__ float sEgl[32];

  const int tid = threadIdx.x;
  const int ch = blockIdx.x;
  const int c = ch >> 5, bh = ch & 31;
  const int b = bh >> 4, h = bh & 15;
  const int t0 = c*64;
  const int iq = tid >> 2, kq = (tid & 3)*8;

  float* wsW = ws;
  float* wsU = ws + OFF_U;
  float* wsM = ws + OFF_M;
  float* wsCc= ws + OFF_C;

  const float negA = -__expf(A_log[h]);

  { // gate g into sG
    const float* gr = graw + (((size_t)b*Tt + t0 + iq)*Hh + h)*32 + kq;
    const float* db = dt_bias + h*32 + kq;
    #pragma unroll
    for (int r = 0; r < 8; ++r)
      sG[iq*33 + kq + r] = negA * softplusf(gr[r] + db[r]);
  }
  __syncthreads();
  if (tid < 32) { // cumsum over time per k
    float acc = 0.f;
    for (int i = 0; i < 64; ++i) { acc += sG[i*33 + tid]; sG[i*33 + tid] = acc; }
  }
  { // k row-l2-normalize into sK
    const float* kp = kin + (((size_t)b*Tt + t0 + iq)*Hh + h)*32 + kq;
    float kr[8]; float ss = 0.f;
    #pragma unroll
    for (int r = 0; r < 8; ++r) { kr[r] = kp[r]; ss += kr[r]*kr[r]; }
    ss += __shfl_xor(ss, 1); ss += __shfl_xor(ss, 2);
    const float sc = 1.f / fmaxf(sqrtf(ss), 1e-6f);
    #pragma unroll
    for (int r = 0; r < 8; ++r) sK[iq*33 + kq + r] = kr[r]*sc;
  }
  __syncthreads();

  // ---- Akk in 8-column tiles: decay factorized about r = gcum[j0] ----
  const float b_cm = beta[((size_t)b*Tt + t0 + (tid & 63))*Hh + h];
  float* P = sT;            // 64x32 stride 33
  float* Q = sT + 2112;     // 8x32 stride 33
  for (int jt = 0; jt < 8; ++jt) {
    const int j0 = jt*8;
    #pragma unroll
    for (int r = 0; r < 8; ++r) {
      const int idx = iq*33 + kq + r;
      P[idx] = sK[idx] * __expf(fminf(sG[idx] - sG[j0*33 + kq + r], 0.f));
    }
    {
      const int jj = tid >> 5, kk = tid & 31;
      Q[jj*33 + kk] = sK[(j0+jj)*33 + kk] * __expf(sG[j0*33 + kk] - sG[(j0+jj)*33 + kk]);
    }
    __syncthreads();
    {
      const int i = tid & 63, jj2 = (tid >> 6)*2;
      float a0 = 0.f, a1 = 0.f;
      for (int kk = 0; kk < 32; ++kk) {
        const float p = P[i*33 + kk];
        a0 += p * Q[(jj2  )*33 + kk];
        a1 += p * Q[(jj2+1)*33 + kk];
      }
      const int j_0 = j0 + jj2;
      sL[(j_0  )*64 + i] = (i > j_0  ) ? a0*b_cm : 0.f;
      sL[(j_0+1)*64 + i] = (i > j_0+1) ? a1*b_cm : 0.f;
    }
    __syncthreads();
  }

  // ---- Tm = (I + L)^-1, blocked 16x16 forward substitution ----
  for (int e = tid; e < 4096; e += 256) {
    const int row = e >> 6, col = e & 63;
    sT[row*65 + col] = (row == col) ? 1.f : 0.f;
  }
  __syncthreads();
  { // diagonal blocks
    const int p = tid >> 4, col = tid & 15;
    for (int i = 1; i < 16; ++i) {
      if (tid < 64) {
        const int gi = p*16 + i, gc = p*16 + col;
        float acc = 0.f;
        for (int j = 0; j < i; ++j)
          acc -= sL[(p*16+j)*64 + gi] * sT[(p*16+j)*65 + gc];
        sT[gi*65 + gc] = acc + ((i == col) ? 1.f : 0.f);
      }
      __syncthreads();
    }
  }
  { // off-diagonal blocks
    const int ri = tid >> 4, col = tid & 15;
    for (int d = 1; d <= 3; ++d)
      for (int p = d; p < 4; ++p) {
        const int q = p - d;
        float acc = 0.f;
        for (int m = q; m < p; ++m) {
          #pragma unroll
          for (int j = 0; j < 16; ++j)
            acc += sL[(m*16+j)*64 + (p*16+ri)] * sT[(m*16+j)*65 + (q*16+col)];
        }
        sC[ri*17 + col] = acc;
        __syncthreads();
        float acc2 = 0.f;
        #pragma unroll
        for (int j = 0; j < 16; ++j)
          acc2 += sT[(p*16+ri)*65 + (p*16+j)] * sC[j*17 + col];
        sT[(p*16+ri)*65 + (q*16+col)] = -acc2;
        __syncthreads();
      }
  }

  { // k_egb into sL(s33); kd overwrites sK; egl into sEgl
    const float b_row = beta[((size_t)b*Tt + t0 + iq)*Hh + h];
    #pragma unroll
    for (int r = 0; r < 8; ++r) {
      const int idx = iq*33 + kq + r;
      const float g = sG[idx], kn = sK[idx];
      sL[idx] = b_row * kn * __expf(g);
      sK[idx] = kn * __expf(sG[63*33 + kq + r] - g);
    }
    if (tid < 32) sEgl[tid] = __expf(sG[63*33 + tid]);
  }
  __syncthreads();

  { // w = Tm @ k_egb -> wsW and into sG (overwrites gcum, now dead)
    float acc[8] = {0,0,0,0,0,0,0,0};
    for (int j = 0; j <= iq; ++j) {
      const float t = sT[iq*65 + j];
      #pragma unroll
      for (int r = 0; r < 8; ++r) acc[r] += t * sL[j*33 + kq + r];
    }
    #pragma unroll
    for (int r = 0; r < 8; ++r) {
      wsW[(size_t)ch*2048 + tid*8 + r] = acc[r];
      sG[iq*33 + kq + r] = acc[r];
    }
  }
  __syncthreads();

  { // vb = beta_j * v into sL (stride 64)
    #pragma unroll
    for (int r = 0; r < 4; ++r) {
      const int f = tid + 256*r;
      const int j = f >> 4, qd = f & 15;
      const float bj = beta[((size_t)b*Tt + t0 + j)*Hh + h];
      float4 v4 = *(const float4*)(vin + (((size_t)b*Tt + t0 + j)*Hh + h)*64 + qd*4);
      v4.x *= bj; v4.y *= bj; v4.z *= bj; v4.w *= bj;
      *(float4*)(sL + j*64 + qd*4) = v4;
    }
  }
  __syncthreads();

  float uacc[16];
  { // u = Tm @ vb -> wsU (and regs)
    const int vs = (tid & 3)*16;
    #pragma unroll
    for (int r = 0; r < 16; ++r) uacc[r] = 0.f;
    for (int j = 0; j <= iq; ++j) {
      const float t = sT[iq*65 + j];
      #pragma unroll
      for (int r = 0; r < 16; ++r) uacc[r] += t * sL[j*64 + vs + r];
    }
    #pragma unroll
    for (int r = 0; r < 16; ++r) wsU[(size_t)ch*4096 + tid*16 + r] = uacc[r];
  }
  __syncthreads();       // all vb reads done
  { // u into sL (s64)
    const int vs = (tid & 3)*16;
    #pragma unroll
    for (int rr = 0; rr < 4; ++rr) {
      float4 o4; o4.x=uacc[rr*4]; o4.y=uacc[rr*4+1]; o4.z=uacc[rr*4+2]; o4.w=uacc[rr*4+3];
      *(float4*)(sL + iq*64 + vs + rr*4) = o4;
    }
  }
  __syncthreads();

  { // M = diag(egl) - Kd^T W ; C = Kd^T U
    const int a = tid >> 3, b4 = (tid & 7)*4, v8 = (tid & 7)*8;
    float mA[4] = {0,0,0,0};
    float cA[8] = {0,0,0,0,0,0,0,0};
    for (int t = 0; t < 64; ++t) {
      const float kd = sK[t*33 + a];
      #pragma unroll
      for (int r = 0; r < 4; ++r) mA[r] += kd * sG[t*33 + b4 + r];
      #pragma unroll
      for (int r = 0; r < 8; ++r) cA[r] += kd * sL[t*64 + v8 + r];
    }
    float4 m4;
    m4.x = ((a == b4+0) ? sEgl[a] : 0.f) - mA[0];
    m4.y = ((a == b4+1) ? sEgl[a] : 0.f) - mA[1];
    m4.z = ((a == b4+2) ? sEgl[a] : 0.f) - mA[2];
    m4.w = ((a == b4+3) ? sEgl[a] : 0.f) - mA[3];
    *(float4*)(wsM + (size_t)ch*1024 + tid*4) = m4;
    float4 c0, c1;
    c0.x=cA[0]; c0.y=cA[1]; c0.z=cA[2]; c0.w=cA[3];
    c1.x=cA[4]; c1.y=cA[5]; c1.z=cA[6]; c1.w=cA[7];
    *(float4*)(wsCc + (size_t)ch*2048 + tid*8) = c0;
    *(float4*)(wsCc + (size_t)ch*2048 + tid*8 + 4) = c1;
  }
}

// ---------------- scanA: compose 16 chunk maps per segment ----------------
__global__ __launch_bounds__(256) void kda_scanA(float* __restrict__ ws)
{
  __shared__ float sMa[32*33];
  __shared__ float sCa[32*64];
  __shared__ float sMc[32*33];
  __shared__ float sCc[32*64];
  const int tid = threadIdx.x;
  const int bh = blockIdx.x >> 3, seg = blockIdx.x & 7;
  const int a = tid >> 3, b4 = (tid & 7)*4, v8 = (tid & 7)*8;
  const float* wsM = ws + OFF_M;
  const float* wsC = ws + OFF_C;

  #pragma unroll
  for (int r = 0; r < 4; ++r) sMa[a*33 + b4 + r] = (a == b4 + r) ? 1.f : 0.f;
  #pragma unroll
  for (int r = 0; r < 8; ++r) sCa[a*64 + v8 + r] = 0.f;
  __syncthreads();

  for (int i = 0; i < 16; ++i) {
    const int ch = (seg*16 + i)*32 + bh;
    float4 m4 = *(const float4*)(wsM + (size_t)ch*1024 + tid*4);
    float4 c0 = *(const float4*)(wsC + (size_t)ch*2048 + tid*8);
    float4 c1 = *(const float4*)(wsC + (size_t)ch*2048 + tid*8 + 4);
    sMc[a*33+b4+0]=m4.x; sMc[a*33+b4+1]=m4.y; sMc[a*33+b4+2]=m4.z; sMc[a*33+b4+3]=m4.w;
    sCc[a*64+v8+0]=c0.x; sCc[a*64+v8+1]=c0.y; sCc[a*64+v8+2]=c0.z; sCc[a*64+v8+3]=c0.w;
    sCc[a*64+v8+4]=c1.x; sCc[a*64+v8+5]=c1.y; sCc[a*64+v8+6]=c1.z; sCc[a*64+v8+7]=c1.w;
    __syncthreads();
    float cn0=0,cn1=0,cn2=0,cn3=0,cn4=0,cn5=0,cn6=0,cn7=0;
    float mn0=0,mn1=0,mn2=0,mn3=0;
    for (int bb = 0; bb < 32; ++bb) {
      const float m = sMc[a*33 + bb];
      const float4 s0 = *(const float4*)(sCa + bb*64 + v8);
      const float4 s1 = *(const float4*)(sCa + bb*64 + v8 + 4);
      cn0 += m*s0.x; cn1 += m*s0.y; cn2 += m*s0.z; cn3 += m*s0.w;
      cn4 += m*s1.x; cn5 += m*s1.y; cn6 += m*s1.z; cn7 += m*s1.w;
      mn0 += m*sMa[bb*33+b4+0]; mn1 += m*sMa[bb*33+b4+1];
      mn2 += m*sMa[bb*33+b4+2]; mn3 += m*sMa[bb*33+b4+3];
    }
    cn0 += sCc[a*64+v8+0]; cn1 += sCc[a*64+v8+1]; cn2 += sCc[a*64+v8+2]; cn3 += sCc[a*64+v8+3];
    cn4 += sCc[a*64+v8+4]; cn5 += sCc[a*64+v8+5]; cn6 += sCc[a*64+v8+6]; cn7 += sCc[a*64+v8+7];
    __syncthreads();
    sCa[a*64+v8+0]=cn0; sCa[a*64+v8+1]=cn1; sCa[a*64+v8+2]=cn2; sCa[a*64+v8+3]=cn3;
    sCa[a*64+v8+4]=cn4; sCa[a*64+v8+5]=cn5; sCa[a*64+v8+6]=cn6; sCa[a*64+v8+7]=cn7;
    sMa[a*33+b4+0]=mn0; sMa[a*33+b4+1]=mn1; sMa[a*33+b4+2]=mn2; sMa[a*33+b4+3]=mn3;
    __syncthreads();
  }
  const size_t sid = (size_t)(bh*8 + seg);
  float* wsMs = ws + OFF_MS;
  float* wsCs = ws + OFF_CS;
  #pragma unroll
  for (int r = 0; r < 4; ++r) wsMs[sid*1024 + tid*4 + r] = sMa[a*33+b4+r];
  #pragma unroll
  for (int r = 0; r < 8; ++r) wsCs[sid*2048 + tid*8 + r] = sCa[a*64+v8+r];
}

// ---------------- scanB: scan 8 segments per bh ----------------
__global__ __launch_bounds__(256) void kda_scanB(float* __restrict__ ws)
{
  __shared__ float sS[32*64];
  __shared__ float sM[32*33];
  __shared__ float sC2[32*64];
  const int tid = threadIdx.x;
  const int bh = blockIdx.x;
  const int a = tid >> 3, b4 = (tid & 7)*4, v8 = (tid & 7)*8;
  const float* wsMs = ws + OFF_MS;
  const float* wsCs = ws + OFF_CS;
  float* wsSs = ws + OFF_SS;

  #pragma unroll
  for (int r = 0; r < 8; ++r) sS[a*64 + v8 + r] = 0.f;
  __syncthreads();
  for (int seg = 0; seg < 8; ++seg) {
    const size_t sid = (size_t)(bh*8 + seg);
    #pragma unroll
    for (int r = 0; r < 8; ++r) wsSs[sid*2048 + tid*8 + r] = sS[a*64+v8+r];
    float4 m4 = *(const float4*)(wsMs + sid*1024 + tid*4);
    float4 c0 = *(const float4*)(wsCs + sid*2048 + tid*8);
    float4 c1 = *(const float4*)(wsCs + sid*2048 + tid*8 + 4);
    sM[a*33+b4+0]=m4.x; sM[a*33+b4+1]=m4.y; sM[a*33+b4+2]=m4.z; sM[a*33+b4+3]=m4.w;
    sC2[a*64+v8+0]=c0.x; sC2[a*64+v8+1]=c0.y; sC2[a*64+v8+2]=c0.z; sC2[a*64+v8+3]=c0.w;
    sC2[a*64+v8+4]=c1.x; sC2[a*64+v8+5]=c1.y; sC2[a*64+v8+6]=c1.z; sC2[a*64+v8+7]=c1.w;
    __syncthreads();
    float n0=0,n1=0,n2=0,n3=0,n4=0,n5=0,n6=0,n7=0;
    for (int bb = 0; bb < 32; ++bb) {
      const float m = sM[a*33 + bb];
      const float4 s0 = *(const float4*)(sS + bb*64 + v8);
      const float4 s1 = *(const float4*)(sS + bb*64 + v8 + 4);
      n0 += m*s0.x; n1 += m*s0.y; n2 += m*s0.z; n3 += m*s0.w;
      n4 += m*s1.x; n5 += m*s1.y; n6 += m*s1.z; n7 += m*s1.w;
    }
    n0 += sC2[a*64+v8+0]; n1 += sC2[a*64+v8+1]; n2 += sC2[a*64+v8+2]; n3 += sC2[a*64+v8+3];
    n4 += sC2[a*64+v8+4]; n5 += sC2[a*64+v8+5]; n6 += sC2[a*64+v8+6]; n7 += sC2[a*64+v8+7];
    __syncthreads();
    sS[a*64+v8+0]=n0; sS[a*64+v8+1]=n1; sS[a*64+v8+2]=n2; sS[a*64+v8+3]=n3;
    sS[a*64+v8+4]=n4; sS[a*64+v8+5]=n5; sS[a*64+v8+6]=n6; sS[a*64+v8+7]=n7;
    __syncthreads();
  }
}

// ---------------- scanC: replay chunks, emit entering-S and v_new ----------------
__global__ __launch_bounds__(256) void kda_scanC(float* __restrict__ ws)
{
  __shared__ float sS[32*64];
  __shared__ float sW[64*33];
  __shared__ float sM[32*33];
  __shared__ float sC2[32*64];
  const int tid = threadIdx.x;
  const int bh = blockIdx.x >> 3, seg = blockIdx.x & 7;
  const int a = tid >> 3, b4 = (tid & 7)*4, v8 = (tid & 7)*8;
  const int t = tid >> 2, v0 = (tid & 3)*16, kc = (tid & 3)*8;
  float* wsW = ws;
  float* wsU = ws + OFF_U;
  const float* wsM = ws + OFF_M;
  const float* wsC = ws + OFF_C;
  const float* wsSs = ws + OFF_SS;

  const size_t sid = (size_t)(bh*8 + seg);
  #pragma unroll
  for (int r = 0; r < 8; ++r) sS[a*64 + v8 + r] = wsSs[sid*2048 + tid*8 + r];
  __syncthreads();

  for (int i = 0; i < 16; ++i) {
    const int ch = (seg*16 + i)*32 + bh;
    // stage W (row t, cols kc..kc+7), M, C
    float4 w0 = *(const float4*)(wsW + (size_t)ch*2048 + tid*8);
    float4 w1 = *(const float4*)(wsW + (size_t)ch*2048 + tid*8 + 4);
    sW[t*33+kc+0]=w0.x; sW[t*33+kc+1]=w0.y; sW[t*33+kc+2]=w0.z; sW[t*33+kc+3]=w0.w;
    sW[t*33+kc+4]=w1.x; sW[t*33+kc+5]=w1.y; sW[t*33+kc+6]=w1.z; sW[t*33+kc+7]=w1.w;
    float4 m4 = *(const float4*)(wsM + (size_t)ch*1024 + tid*4);
    float4 c0 = *(const float4*)(wsC + (size_t)ch*2048 + tid*8);
    float4 c1 = *(const float4*)(wsC + (size_t)ch*2048 + tid*8 + 4);
    sM[a*33+b4+0]=m4.x; sM[a*33+b4+1]=m4.y; sM[a*33+b4+2]=m4.z; sM[a*33+b4+3]=m4.w;
    sC2[a*64+v8+0]=c0.x; sC2[a*64+v8+1]=c0.y; sC2[a*64+v8+2]=c0.z; sC2[a*64+v8+3]=c0.w;
    sC2[a*64+v8+4]=c1.x; sC2[a*64+v8+5]=c1.y; sC2[a*64+v8+6]=c1.z; sC2[a*64+v8+7]=c1.w;
    float4 A0 = *(const float4*)(wsU + (size_t)ch*4096 + tid*16);
    float4 A1 = *(const float4*)(wsU + (size_t)ch*4096 + tid*16 + 4);
    float4 A2 = *(const float4*)(wsU + (size_t)ch*4096 + tid*16 + 8);
    float4 A3 = *(const float4*)(wsU + (size_t)ch*4096 + tid*16 + 12);
    __syncthreads();

    // v_new = U - W @ S  (row t, cols v0..v0+15)
    for (int bb = 0; bb < 32; ++bb) {
      const float wv = sW[t*33 + bb];
      const float4 s0 = *(const float4*)(sS + bb*64 + v0);
      const float4 s1 = *(const float4*)(sS + bb*64 + v0 + 4);
      const float4 s2 = *(const float4*)(sS + bb*64 + v0 + 8);
      const float4 s3 = *(const float4*)(sS + bb*64 + v0 + 12);
      A0.x -= wv*s0.x; A0.y -= wv*s0.y; A0.z -= wv*s0.z; A0.w -= wv*s0.w;
      A1.x -= wv*s1.x; A1.y -= wv*s1.y; A1.z -= wv*s1.z; A1.w -= wv*s1.w;
      A2.x -= wv*s2.x; A2.y -= wv*s2.y; A2.z -= wv*s2.z; A2.w -= wv*s2.w;
      A3.x -= wv*s3.x; A3.y -= wv*s3.y; A3.z -= wv*s3.z; A3.w -= wv*s3.w;
    }
    *(float4*)(wsU + (size_t)ch*4096 + tid*16)      = A0;
    *(float4*)(wsU + (size_t)ch*4096 + tid*16 + 4)  = A1;
    *(float4*)(wsU + (size_t)ch*4096 + tid*16 + 8)  = A2;
    *(float4*)(wsU + (size_t)ch*4096 + tid*16 + 12) = A3;
    // entering S into the (now consumed) W slot, row-major 32x64
    #pragma unroll
    for (int r = 0; r < 8; ++r) wsW[(size_t)ch*2048 + tid*8 + r] = sS[a*64+v8+r];
    // S = M @ S + C
    float n0=0,n1=0,n2=0,n3=0,n4=0,n5=0,n6=0,n7=0;
    for (int bb = 0; bb < 32; ++bb) {
      const float m = sM[a*33 + bb];
      const float4 s0 = *(const float4*)(sS + bb*64 + v8);
      const float4 s1 = *(const float4*)(sS + bb*64 + v8 + 4);
      n0 += m*s0.x; n1 += m*s0.y; n2 += m*s0.z; n3 += m*s0.w;
      n4 += m*s1.x; n5 += m*s1.y; n6 += m*s1.z; n7 += m*s1.w;
    }
    n0 += sC2[a*64+v8+0]; n1 += sC2[a*64+v8+1]; n2 += sC2[a*64+v8+2]; n3 += sC2[a*64+v8+3];
    n4 += sC2[a*64+v8+4]; n5 += sC2[a*64+v8+5]; n6 += sC2[a*64+v8+6]; n7 += sC2[a*64+v8+7];
    __syncthreads();
    sS[a*64+v8+0]=n0; sS[a*64+v8+1]=n1; sS[a*64+v8+2]=n2; sS[a*64+v8+3]=n3;
    sS[a*64+v8+4]=n4; sS[a*64+v8+5]=n5; sS[a*64+v8+6]=n6; sS[a*64+v8+7]=n7;
    __syncthreads();
  }
}

// ---------------- Phase 3: Aqk + output ----------------
__global__ __launch_bounds__(256) void kda_phase3(
    const float* __restrict__ qin, const float* __restrict__ kin,
    const float* __restrict__ graw,
    const float* __restrict__ A_log, const float* __restrict__ dt_bias,
    const float* __restrict__ ws, float* __restrict__ out)
{
  __shared__ float sG[64*33];   // gcum -> S (stride 64, 2048 floats)
  __shared__ float sQ[64*33];   // qn -> qg
  __shared__ float sA[64*65];   // Aqk
  __shared__ float sV[64*64];   // P/Q scratch -> v_new

  const int tid = threadIdx.x;
  const int ch = blockIdx.x;
  const int c = ch >> 5, bh = ch & 31;
  const int b = bh >> 4, h = bh & 15;
  const int t0 = c*64;
  const int iq = tid >> 2, kq = (tid & 3)*8;

  const float* wsW = ws;            // entering S (32x64 row-major)
  const float* wsU = ws + OFF_U;    // v_new (64x64 row-major)

  const float negA = -__expf(A_log[h]);
  {
    const float* gr = graw + (((size_t)b*Tt + t0 + iq)*Hh + h)*32 + kq;
    const float* db = dt_bias + h*32 + kq;
    #pragma unroll
    for (int r = 0; r < 8; ++r)
      sG[iq*33 + kq + r] = negA * softplusf(gr[r] + db[r]);
  }
  __syncthreads();
  if (tid < 32) {
    float acc = 0.f;
    for (int i = 0; i < 64; ++i) { acc += sG[i*33 + tid]; sG[i*33 + tid] = acc; }
  }
  float knr[8];
  { // q (l2norm * K^-1/2) into sQ; k (l2norm) kept in registers
    const float* qp = qin + (((size_t)b*Tt + t0 + iq)*Hh + h)*32 + kq;
    float qr[8]; float ssq = 0.f;
    #pragma unroll
    for (int r = 0; r < 8; ++r) { qr[r] = qp[r]; ssq += qr[r]*qr[r]; }
    ssq += __shfl_xor(ssq, 1); ssq += __shfl_xor(ssq, 2);
    const float scq = 0.17677669529663687f / fmaxf(sqrtf(ssq), 1e-6f);
    #pragma unroll
    for (int r = 0; r < 8; ++r) sQ[iq*33 + kq + r] = qr[r]*scq;

    const float* kp = kin + (((size_t)b*Tt + t0 + iq)*Hh + h)*32 + kq;
    float ssk = 0.f;
    #pragma unroll
    for (int r = 0; r < 8; ++r) { knr[r] = kp[r]; ssk += knr[r]*knr[r]; }
    ssk += __shfl_xor(ssk, 1); ssk += __shfl_xor(ssk, 2);
    const float sck = 1.f / fmaxf(sqrtf(ssk), 1e-6f);
    #pragma unroll
    for (int r = 0; r < 8; ++r) knr[r] *= sck;
  }
  __syncthreads();

  float* P  = sV;
  float* Qb = sV + 2112;
  for (int jt = 0; jt < 8; ++jt) {
    const int j0 = jt*8;
    #pragma unroll
    for (int r = 0; r < 8; ++r) {
      const int idx = iq*33 + kq + r;
      P[idx] = sQ[idx] * __expf(fminf(sG[idx] - sG[j0*33 + kq + r], 0.f));
    }
    if (iq >= j0 && iq < j0 + 8) {
      const int jj = iq - j0;
      #pragma unroll
      for (int r = 0; r < 8; ++r)
        Qb[jj*33 + kq + r] = knr[r] * __expf(sG[j0*33 + kq + r] - sG[iq*33 + kq + r]);
    }
    __syncthreads();
    {
      const int i = tid & 63, jj2 = (tid >> 6)*2;
      float a0 = 0.f, a1 = 0.f;
      for (int kk = 0; kk < 32; ++kk) {
        const float p = P[i*33 + kk];
        a0 += p * Qb[(jj2  )*33 + kk];
        a1 += p * Qb[(jj2+1)*33 + kk];
      }
      sA[i*65 + j0+jj2  ] = (i >= j0+jj2  ) ? a0 : 0.f;
      sA[i*65 + j0+jj2+1] = (i >= j0+jj2+1) ? a1 : 0.f;
    }
    __syncthreads();
  }
  { // qg = qn * exp(gcum), in place
    #pragma unroll
    for (int r = 0; r < 8; ++r) {
      const int idx = iq*33 + kq + r;
      sQ[idx] *= __expf(sG[idx]);
    }
  }
  __syncthreads();
  { // load S into sG (s64 flat) and v_new into sV
    #pragma unroll
    for (int rr = 0; rr < 2; ++rr) {
      const int f = tid + 256*rr;
      *(float4*)(sG + f*4) = *(const float4*)(wsW + (size_t)ch*2048 + f*4);
    }
    #pragma unroll
    for (int rr = 0; rr < 4; ++rr) {
      const int f = tid + 256*rr;
      *(float4*)(sV + f*4) = *(const float4*)(wsU + (size_t)ch*4096 + f*4);
    }
  }
  __syncthreads();
  { // o = qg @ S + Aqk @ v_new
    const int vs = (tid & 3)*16;
    float acc[16];
    #pragma unroll
    for (int r = 0; r < 16; ++r) acc[r] = 0.f;
    for (int kk = 0; kk < 32; ++kk) {
      const float qv = sQ[iq*33 + kk];
      #pragma unroll
      for (int r = 0; r < 16; ++r) acc[r] += qv * sG[kk*64 + vs + r];
    }
    for (int j = 0; j <= iq; ++j) {
      const float av = sA[iq*65 + j];
      #pragma unroll
      for (int r = 0; r < 16; ++r) acc[r] += av * sV[j*64 + vs + r];
    }
    float* op = out + (((size_t)b*Tt + t0 + iq)*Hh + h)*64 + vs;
    #pragma unroll
    for (int rr = 0; rr < 4; ++rr) {
      float4 o4; o4.x=acc[rr*4]; o4.y=acc[rr*4+1]; o4.z=acc[rr*4+2]; o4.w=acc[rr*4+3];
      *(float4*)(op + rr*4) = o4;
    }
  }
}

extern "C" void kernel_launch(void* const* d_in, const int* in_sizes, int n_in,
                              void* d_out, int out_size, void* d_ws, size_t ws_size,
                              hipStream_t stream) {
  const float* q    = (const float*)d_in[0];
  const float* k    = (const float*)d_in[1];
  const float* v    = (const float*)d_in[2];
  const float* graw = (const float*)d_in[3];
  const float* beta = (const float*)d_in[4];
  const float* A_log= (const float*)d_in[5];
  const float* dtb  = (const float*)d_in[6];
  float* out = (float*)d_out;
  float* ws  = (float*)d_ws;
  // requires ws_size >= 156.3 MB

  kda_phase1<<<NCH, 256, 0, stream>>>(k, v, graw, beta, A_log, dtb, ws);
  kda_scanA<<<256, 256, 0, stream>>>(ws);
  kda_scanB<<<32, 256, 0, stream>>>(ws);
  kda_scanC<<<256, 256, 0, stream>>>(ws);
  kda_phase3<<<NCH, 256, 0, stream>>>(q, k, graw, A_log, dtb, ws, out);
}

// Round 3
// 572.658 us; speedup vs baseline: 1.2969x; 1.0751x over previous
//
#include <hip/hip_runtime.h>
#include <math.h>

// Problem constants (B,T,H,K,V,BT) = (2,8192,16,32,64,64)
#define Tt 8192
#define Hh 16
#define NCH 4096        // chunk-heads, ch = c*32 + (b*16+h)
// Workspace layout (floats):
//   wsW  [NCH][2048]  w (64x32 row-major)
//   wsU  [NCH][4096]  u (64x64 row-major)
//   wsM  [NCH][1024]  M = diag(egl) - Kd^T W
//   wsC  [NCH][2048]  C = Kd^T U   -> overwritten by entering-S (32x64) in scanC
//   wsMs [256][1024]  per-segment composed M
//   wsCs [256][2048]  per-segment composed C
//   wsSs [256][2048]  entering S per segment
// total = (4096*9216 + 256*5120)*4 B = 156.3 MB

#define OFF_U   ((size_t)NCH*2048)
#define OFF_M   ((size_t)NCH*6144)
#define OFF_C   ((size_t)NCH*7168)
#define OFF_MS  ((size_t)NCH*9216)
#define OFF_CS  (OFF_MS + (size_t)256*1024)
#define OFF_SS  (OFF_CS + (size_t)256*2048)

__device__ __forceinline__ float softplusf(float x) {
  return fmaxf(x, 0.f) + log1pf(__expf(-fabsf(x)));
}

// ---------------- Phase 1: per-chunk intra quantities + (M,C) ----------------
__global__ __launch_bounds__(256) void kda_phase1(
    const float* __restrict__ kin, const float* __restrict__ vin,
    const float* __restrict__ graw, const float* __restrict__ beta,
    const float* __restrict__ A_log, const float* __restrict__ dt_bias,
    float* __restrict__ ws)
{
  __shared__ float sG[64*33];   // gcum (s33) -> W (s32, first 2048)
  __shared__ float sK[64*33];   // kn -> kd (s33)
  __shared__ float sL[64*64];   // L col-major -> k_egb(s32) -> vb(s64) -> u(s64)
  __shared__ float sT[64*65];   // P(s33)+Q(s32 @2112) -> Tm (s65)
  __shared__ float sC2[3*272];  // per-wave off-diag temp
  __shared__ float sEgl[32];

  const int tid = threadIdx.x;
  const int ch = blockIdx.x;
  const int c = ch >> 5, bh = ch & 31;
  const int b = bh >> 4, h = bh & 15;
  const int t0 = c*64;
  const int iq = tid >> 2, kq = (tid & 3)*8;

  float* wsW = ws;
  float* wsU = ws + OFF_U;
  float* wsM = ws + OFF_M;
  float* wsCc= ws + OFF_C;

  const float negA = -__expf(A_log[h]);

  { // gate g into sG
    const float* gr = graw + (((size_t)b*Tt + t0 + iq)*Hh + h)*32 + kq;
    const float* db = dt_bias + h*32 + kq;
    #pragma unroll
    for (int r = 0; r < 8; ++r)
      sG[iq*33 + kq + r] = negA * softplusf(gr[r] + db[r]);
  }
  __syncthreads();
  if (tid < 32) { // cumsum over time per k
    float acc = 0.f;
    for (int i = 0; i < 64; ++i) { acc += sG[i*33 + tid]; sG[i*33 + tid] = acc; }
  }
  { // k row-l2-normalize into sK
    const float* kp = kin + (((size_t)b*Tt + t0 + iq)*Hh + h)*32 + kq;
    float kr[8]; float ss = 0.f;
    #pragma unroll
    for (int r = 0; r < 8; ++r) { kr[r] = kp[r]; ss += kr[r]*kr[r]; }
    ss += __shfl_xor(ss, 1); ss += __shfl_xor(ss, 2);
    const float sc = 1.f / fmaxf(sqrtf(ss), 1e-6f);
    #pragma unroll
    for (int r = 0; r < 8; ++r) sK[iq*33 + kq + r] = kr[r]*sc;
  }
  __syncthreads();

  // ---- Akk in 8-column tiles, Q-rows preloaded to registers ----
  const float b_cm = beta[((size_t)b*Tt + t0 + (tid & 63))*Hh + h];
  float* P  = sT;          // 64x32 s33
  float* Qb = sT + 2112;   // 8x32 s32
  const int i64 = tid & 63, jj2 = (tid >> 6)*2;
  for (int jt = 0; jt < 8; ++jt) {
    const int j0 = jt*8;
    #pragma unroll
    for (int r = 0; r < 8; ++r) {
      const int idx = iq*33 + kq + r;
      P[idx] = sK[idx] * __expf(fminf(sG[idx] - sG[j0*33 + kq + r], 0.f));
    }
    {
      const int jj = tid >> 5, kk = tid & 31;
      Qb[jj*32 + kk] = sK[(j0+jj)*33 + kk] * __expf(sG[j0*33 + kk] - sG[(j0+jj)*33 + kk]);
    }
    __syncthreads();
    float a0 = 0.f, a1 = 0.f;
    #pragma unroll
    for (int hf = 0; hf < 2; ++hf) {
      const int k0 = hf*16;
      float qa[16], qb[16];
      #pragma unroll
      for (int t4 = 0; t4 < 4; ++t4) {
        float4 xa = *(const float4*)(Qb + (jj2  )*32 + k0 + t4*4);
        float4 xb = *(const float4*)(Qb + (jj2+1)*32 + k0 + t4*4);
        qa[t4*4+0]=xa.x; qa[t4*4+1]=xa.y; qa[t4*4+2]=xa.z; qa[t4*4+3]=xa.w;
        qb[t4*4+0]=xb.x; qb[t4*4+1]=xb.y; qb[t4*4+2]=xb.z; qb[t4*4+3]=xb.w;
      }
      #pragma unroll
      for (int kk = 0; kk < 16; ++kk) {
        const float p = P[i64*33 + k0 + kk];
        a0 += p * qa[kk]; a1 += p * qb[kk];
      }
    }
    const int j_0 = j0 + jj2;
    sL[(j_0  )*64 + i64] = (i64 > j_0  ) ? a0*b_cm : 0.f;
    sL[(j_0+1)*64 + i64] = (i64 > j_0+1) ? a1*b_cm : 0.f;
    __syncthreads();
  }

  // ---- Tm = (I + L)^-1, blocked 16x16 forward substitution ----
  for (int e = tid; e < 4096; e += 256) {
    const int row = e >> 6, col = e & 63;
    sT[row*65 + col] = (row == col) ? 1.f : 0.f;
  }
  __syncthreads();
  // diagonal blocks: all cross-iteration deps are lane-local -> no barriers
  if (tid < 64) {
    const int p = tid >> 4, col = tid & 15;
    for (int i = 1; i < 16; ++i) {
      const int gi = p*16 + i, gc = p*16 + col;
      float acc = 0.f;
      for (int j = 0; j < i; ++j)
        acc -= sL[(p*16+j)*64 + gi] * sT[(p*16+j)*65 + gc];
      sT[gi*65 + gc] = acc + ((i == col) ? 1.f : 0.f);
    }
  }
  __syncthreads();
  // off-diagonal blocks: one 16x16 block per wave, 3 barrier levels
  {
    const int wid = tid >> 6;
    const int lane = tid & 63;
    const int ri = lane & 15, c4 = (lane >> 4)*4;
    auto offblk = [&](int p, int q) {
      float a0=0.f, a1=0.f, a2=0.f, a3=0.f;
      for (int m = q; m < p; ++m) {
        #pragma unroll
        for (int j = 0; j < 16; ++j) {
          const float lv = sL[(m*16+j)*64 + p*16+ri];
          const float* tp = sT + (m*16+j)*65 + q*16 + c4;
          a0 += lv*tp[0]; a1 += lv*tp[1]; a2 += lv*tp[2]; a3 += lv*tp[3];
        }
      }
      float* cp = sC2 + wid*272 + ri*17 + c4;
      cp[0]=a0; cp[1]=a1; cp[2]=a2; cp[3]=a3;
      float b0=0.f, b1=0.f, b2=0.f, b3=0.f;
      #pragma unroll
      for (int j = 0; j < 16; ++j) {
        const float tv = sT[(p*16+ri)*65 + p*16 + j];
        const float* cj = sC2 + wid*272 + j*17 + c4;
        b0 += tv*cj[0]; b1 += tv*cj[1]; b2 += tv*cj[2]; b3 += tv*cj[3];
      }
      float* op = sT + (p*16+ri)*65 + q*16 + c4;
      op[0]=-b0; op[1]=-b1; op[2]=-b2; op[3]=-b3;
    };
    if (wid == 0) offblk(1,0); else if (wid == 1) offblk(2,1); else if (wid == 2) offblk(3,2);
    __syncthreads();
    if (wid == 0) offblk(2,0); else if (wid == 1) offblk(3,1);
    __syncthreads();
    if (wid == 0) offblk(3,0);
  }
  __syncthreads();

  { // k_egb (s32 into sL[0..2047]); kd overwrites sK (s33); egl
    const float b_row = beta[((size_t)b*Tt + t0 + iq)*Hh + h];
    #pragma unroll
    for (int r = 0; r < 8; ++r) {
      const int idx = iq*33 + kq + r;
      const float g = sG[idx], kn = sK[idx];
      sL[iq*32 + kq + r] = b_row * kn * __expf(g);
      sK[idx] = kn * __expf(sG[63*33 + kq + r] - g);
    }
    if (tid < 32) sEgl[tid] = __expf(sG[63*33 + tid]);
  }
  __syncthreads();

  { // w = Tm @ k_egb -> global + sG (s32; gcum dead)
    float acc[8] = {0,0,0,0,0,0,0,0};
    for (int j = 0; j <= iq; ++j) {
      const float t = sT[iq*65 + j];
      const float4 e0 = *(const float4*)(sL + j*32 + kq);
      const float4 e1 = *(const float4*)(sL + j*32 + kq + 4);
      acc[0]+=t*e0.x; acc[1]+=t*e0.y; acc[2]+=t*e0.z; acc[3]+=t*e0.w;
      acc[4]+=t*e1.x; acc[5]+=t*e1.y; acc[6]+=t*e1.z; acc[7]+=t*e1.w;
    }
    #pragma unroll
    for (int r = 0; r < 8; ++r) {
      wsW[(size_t)ch*2048 + tid*8 + r] = acc[r];
      sG[iq*32 + kq + r] = acc[r];
    }
  }
  __syncthreads();

  { // vb = beta_j * v into sL (s64)
    #pragma unroll
    for (int r = 0; r < 4; ++r) {
      const int f = tid + 256*r;
      const int j = f >> 4, qd = f & 15;
      const float bj = beta[((size_t)b*Tt + t0 + j)*Hh + h];
      float4 v4 = *(const float4*)(vin + (((size_t)b*Tt + t0 + j)*Hh + h)*64 + qd*4);
      v4.x *= bj; v4.y *= bj; v4.z *= bj; v4.w *= bj;
      *(float4*)(sL + j*64 + qd*4) = v4;
    }
  }
  __syncthreads();

  float uacc[16];
  { // u = Tm @ vb -> wsU (and regs)
    const int vs = (tid & 3)*16;
    #pragma unroll
    for (int r = 0; r < 16; ++r) uacc[r] = 0.f;
    for (int j = 0; j <= iq; ++j) {
      const float t = sT[iq*65 + j];
      const float4 e0 = *(const float4*)(sL + j*64 + vs);
      const float4 e1 = *(const float4*)(sL + j*64 + vs + 4);
      const float4 e2 = *(const float4*)(sL + j*64 + vs + 8);
      const float4 e3 = *(const float4*)(sL + j*64 + vs + 12);
      uacc[0]+=t*e0.x;  uacc[1]+=t*e0.y;  uacc[2]+=t*e0.z;  uacc[3]+=t*e0.w;
      uacc[4]+=t*e1.x;  uacc[5]+=t*e1.y;  uacc[6]+=t*e1.z;  uacc[7]+=t*e1.w;
      uacc[8]+=t*e2.x;  uacc[9]+=t*e2.y;  uacc[10]+=t*e2.z; uacc[11]+=t*e2.w;
      uacc[12]+=t*e3.x; uacc[13]+=t*e3.y; uacc[14]+=t*e3.z; uacc[15]+=t*e3.w;
    }
    #pragma unroll
    for (int rr = 0; rr < 4; ++rr) {
      float4 o4; o4.x=uacc[rr*4]; o4.y=uacc[rr*4+1]; o4.z=uacc[rr*4+2]; o4.w=uacc[rr*4+3];
      *(float4*)(wsU + (size_t)ch*4096 + tid*16 + rr*4) = o4;
    }
  }
  __syncthreads();       // all vb reads done
  { // u into sL (s64)
    const int vs = (tid & 3)*16;
    #pragma unroll
    for (int rr = 0; rr < 4; ++rr) {
      float4 o4; o4.x=uacc[rr*4]; o4.y=uacc[rr*4+1]; o4.z=uacc[rr*4+2]; o4.w=uacc[rr*4+3];
      *(float4*)(sL + iq*64 + vs + rr*4) = o4;
    }
  }
  __syncthreads();

  { // M = diag(egl) - Kd^T W ; C = Kd^T U
    const int a = tid >> 3, b4 = (tid & 7)*4, v8 = (tid & 7)*8;
    float mA[4] = {0,0,0,0};
    float cA[8] = {0,0,0,0,0,0,0,0};
    for (int t = 0; t < 64; ++t) {
      const float kd = sK[t*33 + a];
      const float4 wv = *(const float4*)(sG + t*32 + b4);
      mA[0]+=kd*wv.x; mA[1]+=kd*wv.y; mA[2]+=kd*wv.z; mA[3]+=kd*wv.w;
      const float4 u0 = *(const float4*)(sL + t*64 + v8);
      const float4 u1 = *(const float4*)(sL + t*64 + v8 + 4);
      cA[0]+=kd*u0.x; cA[1]+=kd*u0.y; cA[2]+=kd*u0.z; cA[3]+=kd*u0.w;
      cA[4]+=kd*u1.x; cA[5]+=kd*u1.y; cA[6]+=kd*u1.z; cA[7]+=kd*u1.w;
    }
    float4 m4;
    m4.x = ((a == b4+0) ? sEgl[a] : 0.f) - mA[0];
    m4.y = ((a == b4+1) ? sEgl[a] : 0.f) - mA[1];
    m4.z = ((a == b4+2) ? sEgl[a] : 0.f) - mA[2];
    m4.w = ((a == b4+3) ? sEgl[a] : 0.f) - mA[3];
    *(float4*)(wsM + (size_t)ch*1024 + tid*4) = m4;
    float4 c0, c1;
    c0.x=cA[0]; c0.y=cA[1]; c0.z=cA[2]; c0.w=cA[3];
    c1.x=cA[4]; c1.y=cA[5]; c1.z=cA[6]; c1.w=cA[7];
    *(float4*)(wsCc + (size_t)ch*2048 + tid*8) = c0;
    *(float4*)(wsCc + (size_t)ch*2048 + tid*8 + 4) = c1;
  }
}

// ---------------- scanA: compose 16 chunk maps per segment (V-split x4) ----------------
__global__ __launch_bounds__(256) void kda_scanA(float* __restrict__ ws)
{
  __shared__ float sMa[32*33];
  __shared__ float sMc[32*33];
  __shared__ float sCa[32*18];
  const int tid = threadIdx.x;
  const int vt = blockIdx.x & 3, seg = (blockIdx.x >> 2) & 7, bh = blockIdx.x >> 5;
  const int v0 = vt*16;
  const int a = tid >> 3, b4 = (tid & 7)*4, c2 = (tid & 7)*2;
  const float* wsM = ws + OFF_M;
  const float* wsC = ws + OFF_C;

  #pragma unroll
  for (int r = 0; r < 4; ++r) sMa[a*33 + b4 + r] = (a == b4 + r) ? 1.f : 0.f;
  sCa[a*18 + c2] = 0.f; sCa[a*18 + c2 + 1] = 0.f;
  __syncthreads();

  for (int i = 0; i < 16; ++i) {
    const int ch = (seg*16 + i)*32 + bh;
    float4 m4 = *(const float4*)(wsM + (size_t)ch*1024 + tid*4);
    float2 cc = *(const float2*)(wsC + (size_t)ch*2048 + a*64 + v0 + c2);
    sMc[a*33+b4+0]=m4.x; sMc[a*33+b4+1]=m4.y; sMc[a*33+b4+2]=m4.z; sMc[a*33+b4+3]=m4.w;
    __syncthreads();
    float cn0 = cc.x, cn1 = cc.y;
    float mn0=0.f, mn1=0.f, mn2=0.f, mn3=0.f;
    for (int bb = 0; bb < 32; ++bb) {
      const float m = sMc[a*33 + bb];
      const float2 s2 = *(const float2*)(sCa + bb*18 + c2);
      cn0 += m*s2.x; cn1 += m*s2.y;
      mn0 += m*sMa[bb*33+b4+0]; mn1 += m*sMa[bb*33+b4+1];
      mn2 += m*sMa[bb*33+b4+2]; mn3 += m*sMa[bb*33+b4+3];
    }
    __syncthreads();
    sCa[a*18+c2] = cn0; sCa[a*18+c2+1] = cn1;
    sMa[a*33+b4+0]=mn0; sMa[a*33+b4+1]=mn1; sMa[a*33+b4+2]=mn2; sMa[a*33+b4+3]=mn3;
    __syncthreads();
  }
  const size_t sid = (size_t)(bh*8 + seg);
  float* wsMs = ws + OFF_MS;
  float* wsCs = ws + OFF_CS;
  if (vt == 0) {
    #pragma unroll
    for (int r = 0; r < 4; ++r) wsMs[sid*1024 + tid*4 + r] = sMa[a*33+b4+r];
  }
  float2 co; co.x = sCa[a*18+c2]; co.y = sCa[a*18+c2+1];
  *(float2*)(wsCs + sid*2048 + a*64 + v0 + c2) = co;
}

// ---------------- scanB: scan 8 segments per bh ----------------
__global__ __launch_bounds__(256) void kda_scanB(float* __restrict__ ws)
{
  __shared__ float sS[32*64];
  __shared__ float sM[32*33];
  __shared__ float sC2[32*64];
  const int tid = threadIdx.x;
  const int bh = blockIdx.x;
  const int a = tid >> 3, b4 = (tid & 7)*4, v8 = (tid & 7)*8;
  const float* wsMs = ws + OFF_MS;
  const float* wsCs = ws + OFF_CS;
  float* wsSs = ws + OFF_SS;

  #pragma unroll
  for (int r = 0; r < 8; ++r) sS[a*64 + v8 + r] = 0.f;
  __syncthreads();
  for (int seg = 0; seg < 8; ++seg) {
    const size_t sid = (size_t)(bh*8 + seg);
    #pragma unroll
    for (int r = 0; r < 8; ++r) wsSs[sid*2048 + tid*8 + r] = sS[a*64+v8+r];
    float4 m4 = *(const float4*)(wsMs + sid*1024 + tid*4);
    float4 c0 = *(const float4*)(wsCs + sid*2048 + tid*8);
    float4 c1 = *(const float4*)(wsCs + sid*2048 + tid*8 + 4);
    sM[a*33+b4+0]=m4.x; sM[a*33+b4+1]=m4.y; sM[a*33+b4+2]=m4.z; sM[a*33+b4+3]=m4.w;
    sC2[a*64+v8+0]=c0.x; sC2[a*64+v8+1]=c0.y; sC2[a*64+v8+2]=c0.z; sC2[a*64+v8+3]=c0.w;
    sC2[a*64+v8+4]=c1.x; sC2[a*64+v8+5]=c1.y; sC2[a*64+v8+6]=c1.z; sC2[a*64+v8+7]=c1.w;
    __syncthreads();
    float n0=0,n1=0,n2=0,n3=0,n4=0,n5=0,n6=0,n7=0;
    for (int bb = 0; bb < 32; ++bb) {
      const float m = sM[a*33 + bb];
      const float4 s0 = *(const float4*)(sS + bb*64 + v8);
      const float4 s1 = *(const float4*)(sS + bb*64 + v8 + 4);
      n0 += m*s0.x; n1 += m*s0.y; n2 += m*s0.z; n3 += m*s0.w;
      n4 += m*s1.x; n5 += m*s1.y; n6 += m*s1.z; n7 += m*s1.w;
    }
    n0 += sC2[a*64+v8+0]; n1 += sC2[a*64+v8+1]; n2 += sC2[a*64+v8+2]; n3 += sC2[a*64+v8+3];
    n4 += sC2[a*64+v8+4]; n5 += sC2[a*64+v8+5]; n6 += sC2[a*64+v8+6]; n7 += sC2[a*64+v8+7];
    __syncthreads();
    sS[a*64+v8+0]=n0; sS[a*64+v8+1]=n1; sS[a*64+v8+2]=n2; sS[a*64+v8+3]=n3;
    sS[a*64+v8+4]=n4; sS[a*64+v8+5]=n5; sS[a*64+v8+6]=n6; sS[a*64+v8+7]=n7;
    __syncthreads();
  }
}

// ---------------- scanC: replay chunks, write entering-S over C slot (V-split x4) ----------------
__global__ __launch_bounds__(256) void kda_scanC(float* __restrict__ ws)
{
  __shared__ float sM[32*33];
  __shared__ float sS[32*18];
  const int tid = threadIdx.x;
  const int vt = blockIdx.x & 3, seg = (blockIdx.x >> 2) & 7, bh = blockIdx.x >> 5;
  const int v0 = vt*16;
  const int a = tid >> 3, b4 = (tid & 7)*4, c2 = (tid & 7)*2;
  const float* wsM = ws + OFF_M;
  float* wsC = ws + OFF_C;
  const float* wsSs = ws + OFF_SS;

  const size_t sid = (size_t)(bh*8 + seg);
  {
    float2 s0 = *(const float2*)(wsSs + sid*2048 + a*64 + v0 + c2);
    sS[a*18 + c2] = s0.x; sS[a*18 + c2 + 1] = s0.y;
  }
  __syncthreads();

  for (int i = 0; i < 16; ++i) {
    const int ch = (seg*16 + i)*32 + bh;
    float4 m4 = *(const float4*)(wsM + (size_t)ch*1024 + tid*4);
    float2 cc = *(const float2*)(wsC + (size_t)ch*2048 + a*64 + v0 + c2);
    sM[a*33+b4+0]=m4.x; sM[a*33+b4+1]=m4.y; sM[a*33+b4+2]=m4.z; sM[a*33+b4+3]=m4.w;
    // entering-S over the consumed C slice (disjoint per block; own elements)
    float2 se; se.x = sS[a*18+c2]; se.y = sS[a*18+c2+1];
    *(float2*)(wsC + (size_t)ch*2048 + a*64 + v0 + c2) = se;
    __syncthreads();
    float n0 = cc.x, n1 = cc.y;
    for (int bb = 0; bb < 32; ++bb) {
      const float m = sM[a*33 + bb];
      const float2 s2 = *(const float2*)(sS + bb*18 + c2);
      n0 += m*s2.x; n1 += m*s2.y;
    }
    __syncthreads();
    sS[a*18+c2] = n0; sS[a*18+c2+1] = n1;
    __syncthreads();
  }
}

// ---------------- Phase 3: Aqk + output (o = Aqk@u + (qg - Aqk@w)@S) ----------------
__global__ __launch_bounds__(256) void kda_phase3(
    const float* __restrict__ qin, const float* __restrict__ kin,
    const float* __restrict__ graw,
    const float* __restrict__ A_log, const float* __restrict__ dt_bias,
    const float* __restrict__ ws, float* __restrict__ out)
{
  __shared__ float sG[64*33];   // gcum (s33) -> S (s64, first 2048)
  __shared__ float sQ[64*33];   // qn -> qeff
  __shared__ float sA[64*65];   // Aqk
  __shared__ float sV[64*64];   // P/Qb scratch -> w (s32) -> u (s64)

  const int tid = threadIdx.x;
  const int ch = blockIdx.x;
  const int c = ch >> 5, bh = ch & 31;
  const int b = bh >> 4, h = bh & 15;
  const int t0 = c*64;
  const int iq = tid >> 2, kq = (tid & 3)*8;

  const float* wsW = ws;            // w (64x32)
  const float* wsU = ws + OFF_U;    // u (64x64)
  const float* wsS = ws + OFF_C;    // entering S (32x64) written by scanC

  const float negA = -__expf(A_log[h]);
  {
    const float* gr = graw + (((size_t)b*Tt + t0 + iq)*Hh + h)*32 + kq;
    const float* db = dt_bias + h*32 + kq;
    #pragma unroll
    for (int r = 0; r < 8; ++r)
      sG[iq*33 + kq + r] = negA * softplusf(gr[r] + db[r]);
  }
  __syncthreads();
  if (tid < 32) {
    float acc = 0.f;
    for (int i = 0; i < 64; ++i) { acc += sG[i*33 + tid]; sG[i*33 + tid] = acc; }
  }
  float knr[8];
  { // q (l2norm * K^-1/2) into sQ; k (l2norm) in registers
    const float* qp = qin + (((size_t)b*Tt + t0 + iq)*Hh + h)*32 + kq;
    float qr[8]; float ssq = 0.f;
    #pragma unroll
    for (int r = 0; r < 8; ++r) { qr[r] = qp[r]; ssq += qr[r]*qr[r]; }
    ssq += __shfl_xor(ssq, 1); ssq += __shfl_xor(ssq, 2);
    const float scq = 0.17677669529663687f / fmaxf(sqrtf(ssq), 1e-6f);
    #pragma unroll
    for (int r = 0; r < 8; ++r) sQ[iq*33 + kq + r] = qr[r]*scq;

    const float* kp = kin + (((size_t)b*Tt + t0 + iq)*Hh + h)*32 + kq;
    float ssk = 0.f;
    #pragma unroll
    for (int r = 0; r < 8; ++r) { knr[r] = kp[r]; ssk += knr[r]*knr[r]; }
    ssk += __shfl_xor(ssk, 1); ssk += __shfl_xor(ssk, 2);
    const float sck = 1.f / fmaxf(sqrtf(ssk), 1e-6f);
    #pragma unroll
    for (int r = 0; r < 8; ++r) knr[r] *= sck;
  }
  __syncthreads();

  float* P  = sV;          // s33
  float* Qb = sV + 2112;   // 8x32 s32
  const int i64 = tid & 63, jj2 = (tid >> 6)*2;
  for (int jt = 0; jt < 8; ++jt) {
    const int j0 = jt*8;
    #pragma unroll
    for (int r = 0; r < 8; ++r) {
      const int idx = iq*33 + kq + r;
      P[idx] = sQ[idx] * __expf(fminf(sG[idx] - sG[j0*33 + kq + r], 0.f));
    }
    if (iq >= j0 && iq < j0 + 8) {
      const int jj = iq - j0;
      #pragma unroll
      for (int r = 0; r < 8; ++r)
        Qb[jj*32 + kq + r] = knr[r] * __expf(sG[j0*33 + kq + r] - sG[iq*33 + kq + r]);
    }
    __syncthreads();
    float a0 = 0.f, a1 = 0.f;
    #pragma unroll
    for (int hf = 0; hf < 2; ++hf) {
      const int k0 = hf*16;
      float qa[16], qb[16];
      #pragma unroll
      for (int t4 = 0; t4 < 4; ++t4) {
        float4 xa = *(const float4*)(Qb + (jj2  )*32 + k0 + t4*4);
        float4 xb = *(const float4*)(Qb + (jj2+1)*32 + k0 + t4*4);
        qa[t4*4+0]=xa.x; qa[t4*4+1]=xa.y; qa[t4*4+2]=xa.z; qa[t4*4+3]=xa.w;
        qb[t4*4+0]=xb.x; qb[t4*4+1]=xb.y; qb[t4*4+2]=xb.z; qb[t4*4+3]=xb.w;
      }
      #pragma unroll
      for (int kk = 0; kk < 16; ++kk) {
        const float p = P[i64*33 + k0 + kk];
        a0 += p * qa[kk]; a1 += p * qb[kk];
      }
    }
    const int j_0 = j0 + jj2;
    sA[i64*65 + j_0  ] = (i64 >= j_0  ) ? a0 : 0.f;   // incl. diagonal
    sA[i64*65 + j_0+1] = (i64 >= j_0+1) ? a1 : 0.f;
    __syncthreads();
  }

  float qgr[8];
  { // qg = qn * exp(gcum) in registers (own row slice)
    #pragma unroll
    for (int r = 0; r < 8; ++r) {
      const int idx = iq*33 + kq + r;
      qgr[r] = sQ[idx] * __expf(sG[idx]);
    }
  }
  __syncthreads();   // gcum + sV scratch dead
  { // stage S into sG (s64 flat) and w into sV (s32 flat)
    #pragma unroll
    for (int rr = 0; rr < 2; ++rr) {
      const int f = tid + 256*rr;
      *(float4*)(sG + f*4) = *(const float4*)(wsS + (size_t)ch*2048 + f*4);
    }
    *(float4*)(sV + tid*8)     = *(const float4*)(wsW + (size_t)ch*2048 + tid*8);
    *(float4*)(sV + tid*8 + 4) = *(const float4*)(wsW + (size_t)ch*2048 + tid*8 + 4);
  }
  __syncthreads();
  { // qeff = qg - Aqk @ w  -> sQ
    float qe[8];
    #pragma unroll
    for (int r = 0; r < 8; ++r) qe[r] = qgr[r];
    for (int j = 0; j <= iq; ++j) {
      const float av = sA[iq*65 + j];
      const float4 w0 = *(const float4*)(sV + j*32 + kq);
      const float4 w1 = *(const float4*)(sV + j*32 + kq + 4);
      qe[0]-=av*w0.x; qe[1]-=av*w0.y; qe[2]-=av*w0.z; qe[3]-=av*w0.w;
      qe[4]-=av*w1.x; qe[5]-=av*w1.y; qe[6]-=av*w1.z; qe[7]-=av*w1.w;
    }
    #pragma unroll
    for (int r = 0; r < 8; ++r) sQ[iq*33 + kq + r] = qe[r];
  }
  __syncthreads();   // qeff visible; sV-w reads done
  { // stage u into sV (s64)
    #pragma unroll
    for (int rr = 0; rr < 4; ++rr) {
      const int f = tid + 256*rr;
      *(float4*)(sV + f*4) = *(const float4*)(wsU + (size_t)ch*4096 + f*4);
    }
  }
  __syncthreads();
  { // o = qeff @ S + Aqk @ u
    const int vs = (tid & 3)*16;
    float acc[16];
    #pragma unroll
    for (int r = 0; r < 16; ++r) acc[r] = 0.f;
    for (int kk = 0; kk < 32; ++kk) {
      const float qv = sQ[iq*33 + kk];
      const float4 s0 = *(const float4*)(sG + kk*64 + vs);
      const float4 s1 = *(const float4*)(sG + kk*64 + vs + 4);
      const float4 s2 = *(const float4*)(sG + kk*64 + vs + 8);
      const float4 s3 = *(const float4*)(sG + kk*64 + vs + 12);
      acc[0]+=qv*s0.x;  acc[1]+=qv*s0.y;  acc[2]+=qv*s0.z;  acc[3]+=qv*s0.w;
      acc[4]+=qv*s1.x;  acc[5]+=qv*s1.y;  acc[6]+=qv*s1.z;  acc[7]+=qv*s1.w;
      acc[8]+=qv*s2.x;  acc[9]+=qv*s2.y;  acc[10]+=qv*s2.z; acc[11]+=qv*s2.w;
      acc[12]+=qv*s3.x; acc[13]+=qv*s3.y; acc[14]+=qv*s3.z; acc[15]+=qv*s3.w;
    }
    for (int j = 0; j <= iq; ++j) {
      const float av = sA[iq*65 + j];
      const float4 u0 = *(const float4*)(sV + j*64 + vs);
      const float4 u1 = *(const float4*)(sV + j*64 + vs + 4);
      const float4 u2 = *(const float4*)(sV + j*64 + vs + 8);
      const float4 u3 = *(const float4*)(sV + j*64 + vs + 12);
      acc[0]+=av*u0.x;  acc[1]+=av*u0.y;  acc[2]+=av*u0.z;  acc[3]+=av*u0.w;
      acc[4]+=av*u1.x;  acc[5]+=av*u1.y;  acc[6]+=av*u1.z;  acc[7]+=av*u1.w;
      acc[8]+=av*u2.x;  acc[9]+=av*u2.y;  acc[10]+=av*u2.z; acc[11]+=av*u2.w;
      acc[12]+=av*u3.x; acc[13]+=av*u3.y; acc[14]+=av*u3.z; acc[15]+=av*u3.w;
    }
    float* op = out + (((size_t)b*Tt + t0 + iq)*Hh + h)*64 + vs;
    #pragma unroll
    for (int rr = 0; rr < 4; ++rr) {
      float4 o4; o4.x=acc[rr*4]; o4.y=acc[rr*4+1]; o4.z=acc[rr*4+2]; o4.w=acc[rr*4+3];
      *(float4*)(op + rr*4) = o4;
    }
  }
}

extern "C" void kernel_launch(void* const* d_in, const int* in_sizes, int n_in,
                              void* d_out, int out_size, void* d_ws, size_t ws_size,
                              hipStream_t stream) {
  const float* q    = (const float*)d_in[0];
  const float* k    = (const float*)d_in[1];
  const float* v    = (const float*)d_in[2];
  const float* graw = (const float*)d_in[3];
  const float* beta = (const float*)d_in[4];
  const float* A_log= (const float*)d_in[5];
  const float* dtb  = (const float*)d_in[6];
  float* out = (float*)d_out;
  float* ws  = (float*)d_ws;
  // requires ws_size >= 156.3 MB

  kda_phase1<<<NCH, 256, 0, stream>>>(k, v, graw, beta, A_log, dtb, ws);
  kda_scanA<<<1024, 256, 0, stream>>>(ws);
  kda_scanB<<<32, 256, 0, stream>>>(ws);
  kda_scanC<<<1024, 256, 0, stream>>>(ws);
  kda_phase3<<<NCH, 256, 0, stream>>>(q, k, graw, A_log, dtb, ws, out);
}